// Round 1
// baseline (772.665 us; speedup 1.0000x reference)
//
#include <hip/hip_runtime.h>
#include <math.h>

#define D 256
#define K 1024
#define NROWS 65536
#define MARGIN 0.125f
#define CAND_MAX 256

typedef __bf16 bf16x8 __attribute__((ext_vector_type(8)));
typedef float f32x16 __attribute__((ext_vector_type(16)));

// async global->LDS, 16B per lane; lds base must be wave-uniform, lane i lands at base + i*16
#define GL2LDS16(g, l) __builtin_amdgcn_global_load_lds( \
    (const __attribute__((address_space(1))) char*)(const void*)(g), \
    (__attribute__((address_space(3))) char*)(void*)(l), 16, 0, 0)

__device__ inline float wave_sum_f(float v){
  #pragma unroll
  for (int off = 32; off; off >>= 1) v += __shfl_down(v, off);
  return v;
}
__device__ inline double wave_sum_d(double v){
  #pragma unroll
  for (int off = 32; off; off >>= 1) v += __shfl_down(v, off);
  return v;
}

// ---------------- pass 0a: split x into bf16 hi/lo + row norms ----------------
__global__ __launch_bounds__(256) void split_rows(const float* __restrict__ x,
                                                  __bf16* __restrict__ xh,
                                                  __bf16* __restrict__ xl,
                                                  float* __restrict__ xnorm){
  const int t = threadIdx.x;
  const int w = t >> 6, lane = t & 63;
  const size_t row = (size_t)blockIdx.x * 4 + w;
  const float4 v = *(const float4*)(x + row * D + lane * 4);
  float s = v.x*v.x + v.y*v.y + v.z*v.z + v.w*v.w;
  s = wave_sum_f(s);
  union { __bf16 b[4]; short4 s4; } uh, ul;
  const float vv[4] = {v.x, v.y, v.z, v.w};
  #pragma unroll
  for (int j = 0; j < 4; j++){
    __bf16 h = (__bf16)vv[j];
    uh.b[j] = h;
    ul.b[j] = (__bf16)(vv[j] - (float)h);
  }
  *(short4*)(xh + row * D + lane * 4) = uh.s4;
  *(short4*)(xl + row * D + lane * 4) = ul.s4;
  if (lane == 0) xnorm[row] = s;
}

// ---------------- pass 0b: codebook transpose (fp32 + bf16 hi/lo) + col norms ----------------
__global__ __launch_bounds__(256) void prep_codebook(const float* __restrict__ cb,
                                                     float* __restrict__ cT,
                                                     __bf16* __restrict__ ch,
                                                     __bf16* __restrict__ cl,
                                                     float* __restrict__ cnorm){
  const int k = blockIdx.x;
  const int t = threadIdx.x;
  const int w = t >> 6, lane = t & 63;
  float v = cb[(size_t)t * K + k];
  cT[(size_t)k * D + t] = v;
  __bf16 h = (__bf16)v;
  ch[(size_t)k * D + t] = h;
  cl[(size_t)k * D + t] = (__bf16)(v - (float)h);
  float s = wave_sum_f(v * v);
  __shared__ float red[4];
  if (lane == 0) red[w] = s;
  __syncthreads();
  if (t == 0) cnorm[k] = red[0] + red[1] + red[2] + red[3];
}

// ---------------- fused pass 1: 32-row x 1024-code block, dist never leaves registers ----------
// 512 threads = 8 waves; wave w owns rows[0..32) x codes[w*128 .. w*128+128) via 4x mfma_32x32x16.
// After K-loop: dist -> iv=1/d in regs, row {max iv, sum iv^2} reduced in-block, soft written once.
// Candidates (iv >= 1/(dmin+MARGIN)) spilled to a small global list for the fp64 refine pass.
__global__ __launch_bounds__(512) void vq_fused(
    const __bf16* __restrict__ xh, const __bf16* __restrict__ xl,
    const __bf16* __restrict__ ch, const __bf16* __restrict__ cl,
    const float* __restrict__ cnorm, const float* __restrict__ xnorm,
    float* __restrict__ soft, int* __restrict__ cand_cnt, int* __restrict__ cand_buf)
{
  __shared__ __bf16 Bh[2][K * 16];    // 32 KB each buf -> 64 KB
  __shared__ __bf16 Bl[2][K * 16];    // 64 KB
  __shared__ __bf16 Ah[2][32 * 16];   // 1 KB each
  __shared__ __bf16 Al[2][32 * 16];
  __shared__ float xns[32];
  __shared__ float redmax[8][32];
  __shared__ float redsum[8][32];
  __shared__ float rowilim[32];
  __shared__ float rowrs[32];
  __shared__ int   lcand[CAND_MAX];
  __shared__ int   lcnt;

  const int t = threadIdx.x, w = t >> 6, lane = t & 63;
  const int col = lane & 31, hi = lane >> 5;
  const size_t base = (size_t)blockIdx.x * 32;

  if (t < 32) xns[t] = xnorm[base + t];
  if (t == 0) lcnt = 0;

  auto stageA = [&](int buf, int k0){
    const int row = lane >> 1, part = lane & 1;
    const size_t go = (base + row) * (size_t)D + k0 * 16 + part * 8;
    if (w == 0)      GL2LDS16(xh + go, &Ah[buf][0]);
    else if (w == 1) GL2LDS16(xl + go, &Al[buf][0]);
  };
  auto stageB = [&](int buf, int k0){
    #pragma unroll
    for (int i = 0; i < 4; i++){
      const int li = w * 4 + i;                 // wave-load index 0..31, 32 codes each
      const int code = li * 32 + (lane >> 1);
      const int part = lane & 1;
      const size_t go = (size_t)code * D + k0 * 16 + part * 8;
      GL2LDS16(ch + go, &Bh[buf][li * 512]);
      GL2LDS16(cl + go, &Bl[buf][li * 512]);
    }
  };

  f32x16 acc[4];
  #pragma unroll
  for (int s = 0; s < 4; s++)
    #pragma unroll
    for (int j = 0; j < 16; j++) acc[s][j] = 0.f;

  stageA(0, 0); stageB(0, 0);
  int cur = 0;
  for (int k0 = 0; k0 < 16; k0++){
    __syncthreads();                            // vmcnt drained: buf[cur] landed, buf[cur^1] free
    if (k0 + 1 < 16){ stageA(cur ^ 1, k0 + 1); stageB(cur ^ 1, k0 + 1); }
    const bf16x8 a_h = *(const bf16x8*)&Ah[cur][col * 16 + hi * 8];
    const bf16x8 a_l = *(const bf16x8*)&Al[cur][col * 16 + hi * 8];
    #pragma unroll
    for (int s = 0; s < 4; s++){
      const int c = w * 128 + s * 32 + col;
      const bf16x8 b_h = *(const bf16x8*)&Bh[cur][c * 16 + hi * 8];
      const bf16x8 b_l = *(const bf16x8*)&Bl[cur][c * 16 + hi * 8];
      acc[s] = __builtin_amdgcn_mfma_f32_32x32x16_bf16(a_h, b_h, acc[s], 0, 0, 0);
      acc[s] = __builtin_amdgcn_mfma_f32_32x32x16_bf16(a_h, b_l, acc[s], 0, 0, 0);
      acc[s] = __builtin_amdgcn_mfma_f32_32x32x16_bf16(a_l, b_h, acc[s], 0, 0, 0);
    }
    cur ^= 1;
  }

  // ---- epilogue: sim -> dist -> iv in place; per-row {max iv, sum iv^2} ----
  float cn[4];
  #pragma unroll
  for (int s = 0; s < 4; s++) cn[s] = cnorm[w * 128 + s * 32 + col];

  float pmax[16], psum[16];
  #pragma unroll
  for (int r = 0; r < 16; r++){
    const int row = (r & 3) + 8 * (r >> 2) + 4 * hi;   // m74-verified 32x32 C layout
    const float xn = xns[row];
    float mx = 0.f, sm = 0.f;
    #pragma unroll
    for (int s = 0; s < 4; s++){
      const float d = xn + cn[s] - 2.0f * acc[s][r];
      const float iv = 1.0f / d;
      acc[s][r] = iv;
      mx = fmaxf(mx, iv);
      sm += iv * iv;
    }
    pmax[r] = mx; psum[r] = sm;
  }

  // reduce across the 32 code-columns of this wave (rows replicated per lane-half)
  #pragma unroll
  for (int mask = 1; mask <= 16; mask <<= 1)
    #pragma unroll
    for (int r = 0; r < 16; r++){
      pmax[r] = fmaxf(pmax[r], __shfl_xor(pmax[r], mask));
      psum[r] += __shfl_xor(psum[r], mask);
    }

  if (col == 0){
    #pragma unroll
    for (int r = 0; r < 16; r++){
      const int row = (r & 3) + 8 * (r >> 2) + 4 * hi;
      redmax[w][row] = pmax[r];
      redsum[w][row] = psum[r];
    }
  }
  __syncthreads();
  if (t < 32){
    float mx = 0.f, sm = 0.f;
    #pragma unroll
    for (int ww = 0; ww < 8; ww++){
      mx = fmaxf(mx, redmax[ww][t]);
      sm += redsum[ww][t];
    }
    rowilim[t] = 1.0f / (1.0f / mx + MARGIN);   // iv >= ilim  <=>  d <= dmin + MARGIN
    rowrs[t]   = 1.0f / sm;
  }
  __syncthreads();

  // ---- write soft directly + collect candidates ----
  #pragma unroll
  for (int r = 0; r < 16; r++){
    const int row = (r & 3) + 8 * (r >> 2) + 4 * hi;
    const float ilim = rowilim[row], rs = rowrs[row];
    const size_t rowoff = (base + row) * (size_t)K + w * 128 + col;
    #pragma unroll
    for (int s = 0; s < 4; s++){
      const float iv = acc[s][r];
      soft[rowoff + s * 32] = iv * iv * rs;
      if (iv >= ilim){
        const int p = atomicAdd(&lcnt, 1);
        if (p < CAND_MAX) lcand[p] = (row << 10) | (w * 128 + s * 32 + col);
      }
    }
  }
  __syncthreads();
  const int n = min(lcnt, CAND_MAX);
  if (t == 0) cand_cnt[blockIdx.x] = n;
  for (int i = t; i < n; i += 512)
    cand_buf[(size_t)blockIdx.x * CAND_MAX + i] = lcand[i];
}

// ---------------- pass 2 (lite): fp64-refined argmin among candidates + quantize + loss --------
__global__ __launch_bounds__(256) void vq_refine(
    const float* __restrict__ x, const float* __restrict__ cT,
    const int* __restrict__ cand_cnt, const int* __restrict__ cand_buf,
    float* __restrict__ q_out, double* __restrict__ loss_acc)
{
  __shared__ int    lcand[CAND_MAX];
  __shared__ double cand_d[CAND_MAX];
  __shared__ int    rowbest[32];
  __shared__ double bestd[32];

  const int t = threadIdx.x, w = t >> 6, lane = t & 63;
  const size_t base = (size_t)blockIdx.x * 32;
  const int n = cand_cnt[blockIdx.x];
  for (int i = t; i < n; i += 256)
    lcand[i] = cand_buf[(size_t)blockIdx.x * CAND_MAX + i];
  __syncthreads();

  for (int c = w; c < n; c += 4){
    const int rk = lcand[c], r = rk >> 10, k = rk & 1023;
    const float4 xv = *(const float4*)(x  + (base + r) * (size_t)D + lane * 4);
    const float4 cv = *(const float4*)(cT + (size_t)k * D + lane * 4);
    double s = 0.0, dx;
    dx = (double)xv.x - (double)cv.x; s += dx * dx;
    dx = (double)xv.y - (double)cv.y; s += dx * dx;
    dx = (double)xv.z - (double)cv.z; s += dx * dx;
    dx = (double)xv.w - (double)cv.w; s += dx * dx;
    s = wave_sum_d(s);
    if (lane == 0) cand_d[c] = s;
  }
  __syncthreads();

  if (t < 32){
    double best = 1e300; int bi = 1 << 20;
    for (int c = 0; c < n; c++){
      const int rk = lcand[c];
      if ((rk >> 10) == t){
        const double dd = cand_d[c];
        const int k = rk & 1023;
        if (dd < best || (dd == best && k < bi)){ best = dd; bi = k; }
      }
    }
    rowbest[t] = (bi < K) ? bi : 0;   // OOB safety; impossible in practice
    bestd[t] = best;
  }
  __syncthreads();

  #pragma unroll 4
  for (int r = 0; r < 32; r++)
    q_out[(base + r) * (size_t)D + t] = cT[(size_t)rowbest[r] * D + t];

  if (t == 0){
    double s = 0.0;
    #pragma unroll
    for (int r = 0; r < 32; r++) s += bestd[r];
    atomicAdd(loss_acc, s);
  }
}

// ---------------- finalize loss ----------------
__global__ void finalize_loss(const double* __restrict__ acc, float* __restrict__ out_loss){
  out_loss[0] = (float)(1.25 * acc[0] / (double)((size_t)NROWS * D));
}

extern "C" void kernel_launch(void* const* d_in, const int* in_sizes, int n_in,
                              void* d_out, int out_size, void* d_ws, size_t ws_size,
                              hipStream_t stream) {
  const float* x  = (const float*)d_in[0];   // [65536,256]
  const float* cb = (const float*)d_in[1];   // [256,1024]

  float* out      = (float*)d_out;
  float* q_out    = out;                                          // 16777216
  float* soft     = out + (size_t)NROWS * D;                      // 67108864
  float* loss_out = out + (size_t)NROWS * D + (size_t)NROWS * K;  // 1

  char* ws = (char*)d_ws;
  double* acc      = (double*)ws;                 // @0        (8 B)
  float*  cnorm    = (float*)(ws + 4096);         // 4 KB
  int*    cand_cnt = (int*)(ws + 16384);          // 8 KB
  float*  xnorm    = (float*)(ws + 262144);       // 256 KB
  int*    cand_buf = (int*)(ws + 524288);         // 2 MB
  float*  cT       = (float*)(ws + 2621440);      // 1 MB
  __bf16* ch       = (__bf16*)(ws + 3670016);     // 512 KB
  __bf16* cl       = (__bf16*)(ws + 4194304);     // 512 KB
  __bf16* xh       = (__bf16*)(ws + 4718592);     // 32 MB
  __bf16* xl       = (__bf16*)(ws + 38273024);    // 32 MB  (total ~68.5 MB)

  hipMemsetAsync(acc, 0, sizeof(double), stream);
  split_rows<<<NROWS / 4, 256, 0, stream>>>(x, xh, xl, xnorm);
  prep_codebook<<<K, 256, 0, stream>>>(cb, cT, ch, cl, cnorm);
  vq_fused<<<NROWS / 32, 512, 0, stream>>>(xh, xl, ch, cl, cnorm, xnorm, soft, cand_cnt, cand_buf);
  vq_refine<<<NROWS / 32, 256, 0, stream>>>(x, cT, cand_cnt, cand_buf, q_out, acc);
  finalize_loss<<<1, 1, 0, stream>>>(acc, loss_out);
}

// Round 4
// 634.102 us; speedup vs baseline: 1.2185x; 1.2185x over previous
//
#include <hip/hip_runtime.h>
#include <math.h>

#define D 256
#define K 1024
#define NROWS 65536
#define MARGIN 0.125f
#define CAND_MAX 256

typedef __bf16 bf16x8 __attribute__((ext_vector_type(8)));
typedef float f32x16 __attribute__((ext_vector_type(16)));

// async global->LDS, 16B per lane; lds base must be wave-uniform, lane i lands at base + i*16
// aux=0 only: HW-verified encoding (learn_hip m03/m97). aux=2 (nt) is unverified -> avoided.
#define GL2LDS16(g, l) __builtin_amdgcn_global_load_lds( \
    (const __attribute__((address_space(1))) char*)(const void*)(g), \
    (__attribute__((address_space(3))) char*)(void*)(l), 16, 0, 0)

__device__ inline float wave_sum_f(float v){
  #pragma unroll
  for (int off = 32; off; off >>= 1) v += __shfl_down(v, off);
  return v;
}
__device__ inline double wave_sum_d(double v){
  #pragma unroll
  for (int off = 32; off; off >>= 1) v += __shfl_down(v, off);
  return v;
}

// ---------------- pass 0a: split x into bf16 hi/lo + row norms ----------------
__global__ __launch_bounds__(256) void split_rows(const float* __restrict__ x,
                                                  __bf16* __restrict__ xh,
                                                  __bf16* __restrict__ xl,
                                                  float* __restrict__ xnorm){
  const int t = threadIdx.x;
  const int w = t >> 6, lane = t & 63;
  const size_t row = (size_t)blockIdx.x * 4 + w;
  const float4 v = *(const float4*)(x + row * D + lane * 4);
  float s = v.x*v.x + v.y*v.y + v.z*v.z + v.w*v.w;
  s = wave_sum_f(s);
  union { __bf16 b[4]; short4 s4; } uh, ul;
  const float vv[4] = {v.x, v.y, v.z, v.w};
  #pragma unroll
  for (int j = 0; j < 4; j++){
    __bf16 h = (__bf16)vv[j];
    uh.b[j] = h;
    ul.b[j] = (__bf16)(vv[j] - (float)h);
  }
  *(short4*)(xh + row * D + lane * 4) = uh.s4;
  *(short4*)(xl + row * D + lane * 4) = ul.s4;
  if (lane == 0) xnorm[row] = s;
}

// ---------------- pass 0b: codebook transpose (fp32 + bf16 hi/lo) + col norms ----------------
__global__ __launch_bounds__(256) void prep_codebook(const float* __restrict__ cb,
                                                     float* __restrict__ cT,
                                                     __bf16* __restrict__ ch,
                                                     __bf16* __restrict__ cl,
                                                     float* __restrict__ cnorm){
  const int k = blockIdx.x;
  const int t = threadIdx.x;
  const int w = t >> 6, lane = t & 63;
  float v = cb[(size_t)t * K + k];
  cT[(size_t)k * D + t] = v;
  __bf16 h = (__bf16)v;
  ch[(size_t)k * D + t] = h;
  cl[(size_t)k * D + t] = (__bf16)(v - (float)h);
  float s = wave_sum_f(v * v);
  __shared__ float red[4];
  if (lane == 0) red[w] = s;
  __syncthreads();
  if (t == 0) cnorm[k] = red[0] + red[1] + red[2] + red[3];
}

// ---------------- fused pass 1: 64-row x 1024-code block ----------------------------------
// 512 threads = 8 waves; wave w owns rows[0..64) x codes[w*128 .. +128) via 2x4 mfma_32x32x16
// tiles (acc = 8 x f32x16 = 128 VGPR). B (codebook hi/lo) streamed through dbuf LDS. soft is
// nt-stored so the 256MB write stream doesn't evict the ~2MB codebook working set from L2.
__global__ __launch_bounds__(512, 2) void vq_fused(
    const __bf16* __restrict__ xh, const __bf16* __restrict__ xl,
    const __bf16* __restrict__ ch, const __bf16* __restrict__ cl,
    const float* __restrict__ cnorm, const float* __restrict__ xnorm,
    float* __restrict__ soft, int* __restrict__ cand_cnt, int* __restrict__ cand_buf)
{
  __shared__ __bf16 Bh[2][K * 16];     // 64 KB
  __shared__ __bf16 Bl[2][K * 16];     // 64 KB
  __shared__ __bf16 Ah[2][64 * 16];    // 4 KB
  __shared__ __bf16 Al[2][64 * 16];    // 4 KB
  __shared__ float xns[64];
  __shared__ float redmax[8][64];      // 2 KB
  __shared__ float redsum[8][64];      // 2 KB
  __shared__ float rowilim[64];
  __shared__ float rowrs[64];
  __shared__ int   lcand[CAND_MAX];
  __shared__ int   lcnt;

  const int t = threadIdx.x, w = t >> 6, lane = t & 63;
  const int col = lane & 31, hi = lane >> 5;
  const size_t base = (size_t)blockIdx.x * 64;

  if (t < 64) xns[t] = xnorm[base + t];
  if (t == 0) lcnt = 0;

  auto stageA = [&](int buf, int k0){
    if (w < 4){
      const int row = ((w & 1) << 5) + (lane >> 1), part = lane & 1;
      const size_t go = (base + row) * (size_t)D + k0 * 16 + part * 8;
      __bf16* dst = (w < 2) ? &Ah[buf][(w & 1) * 512] : &Al[buf][(w & 1) * 512];
      const __bf16* src = ((w < 2) ? xh : xl) + go;
      GL2LDS16(src, dst);
    }
  };
  auto stageB = [&](int buf, int k0){
    #pragma unroll
    for (int i = 0; i < 4; i++){
      const int li = w * 4 + i;                 // 0..31, 32 codes each
      const int code = li * 32 + (lane >> 1);
      const size_t go = (size_t)code * D + k0 * 16 + (lane & 1) * 8;
      GL2LDS16(ch + go, &Bh[buf][li * 512]);
      GL2LDS16(cl + go, &Bl[buf][li * 512]);
    }
  };

  f32x16 acc[2][4];
  #pragma unroll
  for (int rt = 0; rt < 2; rt++)
    #pragma unroll
    for (int s = 0; s < 4; s++)
      #pragma unroll
      for (int j = 0; j < 16; j++) acc[rt][s][j] = 0.f;

  stageA(0, 0); stageB(0, 0);
  int cur = 0;
  for (int k0 = 0; k0 < 16; k0++){
    __syncthreads();                            // staged buf[cur] landed; buf[cur^1] free
    if (k0 + 1 < 16){ stageA(cur ^ 1, k0 + 1); stageB(cur ^ 1, k0 + 1); }
    bf16x8 a_h[2], a_l[2];
    #pragma unroll
    for (int rt = 0; rt < 2; rt++){
      const int ro = (rt * 32 + col) * 16 + hi * 8;
      a_h[rt] = *(const bf16x8*)&Ah[cur][ro];
      a_l[rt] = *(const bf16x8*)&Al[cur][ro];
    }
    #pragma unroll
    for (int s = 0; s < 4; s++){
      const int co = (w * 128 + s * 32 + col) * 16 + hi * 8;
      const bf16x8 b_h = *(const bf16x8*)&Bh[cur][co];
      const bf16x8 b_l = *(const bf16x8*)&Bl[cur][co];
      #pragma unroll
      for (int rt = 0; rt < 2; rt++){
        acc[rt][s] = __builtin_amdgcn_mfma_f32_32x32x16_bf16(a_h[rt], b_h, acc[rt][s], 0, 0, 0);
        acc[rt][s] = __builtin_amdgcn_mfma_f32_32x32x16_bf16(a_h[rt], b_l, acc[rt][s], 0, 0, 0);
        acc[rt][s] = __builtin_amdgcn_mfma_f32_32x32x16_bf16(a_l[rt], b_h, acc[rt][s], 0, 0, 0);
      }
    }
    cur ^= 1;
  }

  // ---- epilogue: sim -> dist -> iv in place; per-row {max iv, sum iv^2} ----
  float cn[4];
  #pragma unroll
  for (int s = 0; s < 4; s++) cn[s] = cnorm[w * 128 + s * 32 + col];

  #pragma unroll
  for (int rt = 0; rt < 2; rt++){
    float pmax[16], psum[16];
    #pragma unroll
    for (int r = 0; r < 16; r++){
      const int row = rt * 32 + (r & 3) + 8 * (r >> 2) + 4 * hi;  // m74/m101-verified C layout
      const float xn = xns[row];
      float mx = 0.f, sm = 0.f;
      #pragma unroll
      for (int s = 0; s < 4; s++){
        const float d = xn + cn[s] - 2.0f * acc[rt][s][r];
        const float iv = 1.0f / d;
        acc[rt][s][r] = iv;
        mx = fmaxf(mx, iv);
        sm += iv * iv;
      }
      pmax[r] = mx; psum[r] = sm;
    }
    #pragma unroll
    for (int mask = 1; mask <= 16; mask <<= 1)
      #pragma unroll
      for (int r = 0; r < 16; r++){
        pmax[r] = fmaxf(pmax[r], __shfl_xor(pmax[r], mask));
        psum[r] += __shfl_xor(psum[r], mask);
      }
    if (col == 0){
      #pragma unroll
      for (int r = 0; r < 16; r++){
        const int row = rt * 32 + (r & 3) + 8 * (r >> 2) + 4 * hi;
        redmax[w][row] = pmax[r];
        redsum[w][row] = psum[r];
      }
    }
  }
  __syncthreads();
  if (t < 64){
    float mx = 0.f, sm = 0.f;
    #pragma unroll
    for (int ww = 0; ww < 8; ww++){
      mx = fmaxf(mx, redmax[ww][t]);
      sm += redsum[ww][t];
    }
    rowilim[t] = 1.0f / (1.0f / mx + MARGIN);   // iv >= ilim  <=>  d <= dmin + MARGIN
    rowrs[t]   = 1.0f / sm;
  }
  __syncthreads();

  // ---- write soft directly (nt stores: don't evict the codebook from L2) + candidates ----
  #pragma unroll
  for (int rt = 0; rt < 2; rt++)
    #pragma unroll
    for (int r = 0; r < 16; r++){
      const int row = rt * 32 + (r & 3) + 8 * (r >> 2) + 4 * hi;
      const float ilim = rowilim[row], rs = rowrs[row];
      const size_t rowoff = (base + row) * (size_t)K + w * 128 + col;
      #pragma unroll
      for (int s = 0; s < 4; s++){
        const float iv = acc[rt][s][r];
        __builtin_nontemporal_store(iv * iv * rs, &soft[rowoff + s * 32]);
        if (iv >= ilim){
          const int p = atomicAdd(&lcnt, 1);
          if (p < CAND_MAX) lcand[p] = (row << 10) | (w * 128 + s * 32 + col);
        }
      }
    }
  __syncthreads();
  const int n = min(lcnt, CAND_MAX);
  if (t == 0) cand_cnt[blockIdx.x] = n;
  for (int i = t; i < n; i += 512)
    cand_buf[(size_t)blockIdx.x * CAND_MAX + i] = lcand[i];
}

// ---------------- pass 2 (lite): fp64-refined argmin among candidates + quantize + loss -------
__global__ __launch_bounds__(256) void vq_refine(
    const float* __restrict__ x, const float* __restrict__ cT,
    const int* __restrict__ cand_cnt, const int* __restrict__ cand_buf,
    float* __restrict__ q_out, double* __restrict__ loss_acc)
{
  __shared__ int    lcand[CAND_MAX];
  __shared__ double cand_d[CAND_MAX];
  __shared__ int    rowbest[64];
  __shared__ double bestd[64];

  const int t = threadIdx.x, w = t >> 6, lane = t & 63;
  const size_t base = (size_t)blockIdx.x * 64;
  const int n = cand_cnt[blockIdx.x];
  for (int i = t; i < n; i += 256)
    lcand[i] = cand_buf[(size_t)blockIdx.x * CAND_MAX + i];
  __syncthreads();

  for (int c = w; c < n; c += 4){
    const int rk = lcand[c], r = rk >> 10, k = rk & 1023;
    const float4 xv = *(const float4*)(x  + (base + r) * (size_t)D + lane * 4);
    const float4 cv = *(const float4*)(cT + (size_t)k * D + lane * 4);
    double s = 0.0, dx;
    dx = (double)xv.x - (double)cv.x; s += dx * dx;
    dx = (double)xv.y - (double)cv.y; s += dx * dx;
    dx = (double)xv.z - (double)cv.z; s += dx * dx;
    dx = (double)xv.w - (double)cv.w; s += dx * dx;
    s = wave_sum_d(s);
    if (lane == 0) cand_d[c] = s;
  }
  __syncthreads();

  if (t < 64){
    double best = 1e300; int bi = 1 << 20;
    for (int c = 0; c < n; c++){
      const int rk = lcand[c];
      if ((rk >> 10) == t){
        const double dd = cand_d[c];
        const int k = rk & 1023;
        if (dd < best || (dd == best && k < bi)){ best = dd; bi = k; }
      }
    }
    rowbest[t] = (bi < K) ? bi : 0;   // OOB safety; impossible in practice
    bestd[t] = best;
  }
  __syncthreads();

  #pragma unroll 4
  for (int r = 0; r < 64; r++){
    const float q = cT[(size_t)rowbest[r] * D + t];
    __builtin_nontemporal_store(q, &q_out[(base + r) * (size_t)D + t]);
  }

  if (t == 0){
    double s = 0.0;
    #pragma unroll
    for (int r = 0; r < 64; r++) s += bestd[r];
    atomicAdd(loss_acc, s);
  }
}

// ---------------- finalize loss ----------------
__global__ void finalize_loss(const double* __restrict__ acc, float* __restrict__ out_loss){
  out_loss[0] = (float)(1.25 * acc[0] / (double)((size_t)NROWS * D));
}

extern "C" void kernel_launch(void* const* d_in, const int* in_sizes, int n_in,
                              void* d_out, int out_size, void* d_ws, size_t ws_size,
                              hipStream_t stream) {
  const float* x  = (const float*)d_in[0];   // [65536,256]
  const float* cb = (const float*)d_in[1];   // [256,1024]

  float* out      = (float*)d_out;
  float* q_out    = out;                                          // 16777216
  float* soft     = out + (size_t)NROWS * D;                      // 67108864
  float* loss_out = out + (size_t)NROWS * D + (size_t)NROWS * K;  // 1

  char* ws = (char*)d_ws;
  double* acc      = (double*)ws;                 // @0        (8 B)
  float*  cnorm    = (float*)(ws + 4096);         // 4 KB
  int*    cand_cnt = (int*)(ws + 16384);          // 8 KB
  float*  xnorm    = (float*)(ws + 262144);       // 256 KB
  int*    cand_buf = (int*)(ws + 524288);         // 2 MB region (1 MB used)
  float*  cT       = (float*)(ws + 2621440);      // 1 MB
  __bf16* ch       = (__bf16*)(ws + 3670016);     // 512 KB
  __bf16* cl       = (__bf16*)(ws + 4194304);     // 512 KB
  __bf16* xh       = (__bf16*)(ws + 4718592);     // 32 MB
  __bf16* xl       = (__bf16*)(ws + 38273024);    // 32 MB  (total ~68.5 MB)

  hipMemsetAsync(acc, 0, sizeof(double), stream);
  split_rows<<<NROWS / 4, 256, 0, stream>>>(x, xh, xl, xnorm);
  prep_codebook<<<K, 256, 0, stream>>>(cb, cT, ch, cl, cnorm);
  vq_fused<<<NROWS / 64, 512, 0, stream>>>(xh, xl, ch, cl, cnorm, xnorm, soft, cand_cnt, cand_buf);
  vq_refine<<<NROWS / 64, 256, 0, stream>>>(x, cT, cand_cnt, cand_buf, q_out, acc);
  finalize_loss<<<1, 1, 0, stream>>>(acc, loss_out);
}